// Round 1
// baseline (2913.717 us; speedup 1.0000x reference)
//
#include <hip/hip_runtime.h>

typedef _Float16 half8 __attribute__((ext_vector_type(8)));
typedef float f32x4 __attribute__((ext_vector_type(4)));

union H8U { unsigned long long u[2]; half8 v; };

__device__ __forceinline__ float fast_sigmoid(float v) {
  return 1.0f / (1.0f + __expf(-v));
}
__device__ __forceinline__ float fast_tanh(float v) {
  return 2.0f / (1.0f + __expf(-2.0f * v)) - 1.0f;
}

// ---------------------------------------------------------------------------
// prep: zero barrier flags; build frag-ordered f16 copies of W1, W2.
// Frag layout (for mfma_f32_16x16x32_f16 B operand): flat index
// ((ct*8 + ks)*64 + lane)*8 + s  holds  W[k = ks*32 + (lane>>4)*8 + s][col = ct*16 + (lane&15)]
// so a wave's B-frag load is 64 consecutive 16B lanes (coalesced / conflict-free).
// ---------------------------------------------------------------------------
__global__ void __launch_bounds__(256) prep_kernel(
    const float* __restrict__ W1, const float* __restrict__ W2,
    _Float16* __restrict__ W1f, _Float16* __restrict__ W2f,
    unsigned* __restrict__ flags)
{
  int idx = blockIdx.x * 256 + threadIdx.x;   // grid 512 -> 0..131071
  if (idx < 256)
    __hip_atomic_store(&flags[idx], 0u, __ATOMIC_RELAXED, __HIP_MEMORY_SCOPE_AGENT);
  int m  = idx >> 16;          // 0 -> W1, 1 -> W2
  int i2 = idx & 65535;
  int s = i2 & 7, lane = (i2 >> 3) & 63, ks = (i2 >> 9) & 7, ct = (i2 >> 12) & 15;
  int col = ct * 16 + (lane & 15);
  int k   = ks * 32 + (lane >> 4) * 8 + s;
  float v = (m == 0) ? W1[k * 256 + col] : W2[k * 256 + col];
  _Float16* dst = (m == 0) ? W1f : W2f;
  dst[i2] = (_Float16)v;
}

// ---------------------------------------------------------------------------
// Recurrence: 8 groups (32 batch rows each) x 32 col-WGs (32 gate-cols each).
// grid = 256 blocks of 256 threads. Weight slice resident in LDS (f16).
// Per step: gates[32x32] = [x_t | h_{t-1}] (32x384) @ Wslice (384x32) via MFMA,
// elementwise LSTM update, h_t -> global (agent write-through), flag barrier.
// blockIdx&7 = group  => all 32 WGs of a group land on one XCD (perf only).
// ---------------------------------------------------------------------------
__global__ void __launch_bounds__(256) lstm_rec_kernel(
    const float* __restrict__ x, const float* __restrict__ Wx,
    const float* __restrict__ Wh, const float* __restrict__ bias,
    _Float16* __restrict__ h_all, unsigned* __restrict__ flags)
{
  __shared__ __align__(16) _Float16 Wt[12288];   // frag-linear [2ct][12ks][64lane][8] = 24 KB
  __shared__ __align__(16) _Float16 At[12288];   // frag-linear [2rt][12ks][64lane][8] = 24 KB
  __shared__ float pre_s[32][33];
  __shared__ float c_s[32][8];
  __shared__ float bias_s[32];

  const int tid = threadIdx.x;
  const int g  = blockIdx.x & 7;    // group (heuristically = XCD)
  const int j  = blockIdx.x >> 3;   // column-owner 0..31
  const int b0 = g * 32;            // first batch row of group

  // ---- one-time: stage weight slice (Wx rows 0..127, Wh rows 128..383) as f16 frags
  for (int idx = tid; idx < 384 * 32; idx += 256) {
    int k = idx >> 5, c = idx & 31;          // c = q*8 + d  (q = gate, d = h-dim)
    int q = c >> 3, d = c & 7;
    int gc = q * 256 + j * 8 + d;            // global gate-column
    float v = (k < 128) ? Wx[k * 1024 + gc] : Wh[(k - 128) * 1024 + gc];
    int ctl = c >> 4, lcol = c & 15;
    int ks = k >> 5, kg = (k >> 3) & 3, s = k & 7;
    Wt[(((ctl * 12 + ks) * 64) + kg * 16 + lcol) * 8 + s] = (_Float16)v;
  }
  if (tid < 32) {
    int q = tid >> 3, d = tid & 7;
    bias_s[tid] = bias[q * 256 + j * 8 + d];
  }
  c_s[tid >> 3][tid & 7] = 0.0f;
  __syncthreads();

  const int lane = tid & 63, wid = tid >> 6;
  const int rt = wid & 1, ctw = wid >> 1;          // wave -> 16x16 output tile
  const half8* Af = (const half8*)At + rt * 768 + lane;
  const half8* Bf = (const half8*)Wt + ctw * 768 + lane;
  const int prow = rt * 16 + ((lane >> 4) << 2);
  const int pcol = ctw * 16 + (lane & 15);

  const int srow = tid >> 3, sseg = tid & 7;       // staging: 32 rows x 8 segments
  const int s_rt = srow >> 4, s_lrow = srow & 15;

  H8U zz; zz.u[0] = 0ull; zz.u[1] = 0ull;

  for (int t = 0; t < 512; ++t) {
    // ---- stage x_t (k = 0..127), f32 -> f16 frags
    {
      const float4* xp = (const float4*)(x + ((size_t)(b0 + srow) * 512 + t) * 128 + sseg * 16);
      float4 v0 = xp[0], v1 = xp[1], v2 = xp[2], v3 = xp[3];
      half8 p0, p1;
      p0[0] = (_Float16)v0.x; p0[1] = (_Float16)v0.y; p0[2] = (_Float16)v0.z; p0[3] = (_Float16)v0.w;
      p0[4] = (_Float16)v1.x; p0[5] = (_Float16)v1.y; p0[6] = (_Float16)v1.z; p0[7] = (_Float16)v1.w;
      p1[0] = (_Float16)v2.x; p1[1] = (_Float16)v2.y; p1[2] = (_Float16)v2.z; p1[3] = (_Float16)v2.w;
      p1[4] = (_Float16)v3.x; p1[5] = (_Float16)v3.y; p1[6] = (_Float16)v3.z; p1[7] = (_Float16)v3.w;
      int k0 = sseg * 16;
      int ks = k0 >> 5, kg = (k0 >> 3) & 3;
      ((half8*)At)[(s_rt * 12 + ks) * 64 + kg * 16 + s_lrow]       = p0;
      ((half8*)At)[(s_rt * 12 + ks) * 64 + (kg + 1) * 16 + s_lrow] = p1;
    }
    // ---- stage h_{t-1} (k = 128..383): agent-scope bypass loads (within-kernel exchange)
    {
      half8 q0 = zz.v, q1 = zz.v, q2 = zz.v, q3 = zz.v;
      if (t > 0) {
        const unsigned long long* hp =
            (const unsigned long long*)(h_all + ((size_t)(t - 1) * 256 + b0 + srow) * 256 + sseg * 32);
        H8U c0, c1, c2, c3;
        c0.u[0] = __hip_atomic_load(hp + 0, __ATOMIC_RELAXED, __HIP_MEMORY_SCOPE_AGENT);
        c0.u[1] = __hip_atomic_load(hp + 1, __ATOMIC_RELAXED, __HIP_MEMORY_SCOPE_AGENT);
        c1.u[0] = __hip_atomic_load(hp + 2, __ATOMIC_RELAXED, __HIP_MEMORY_SCOPE_AGENT);
        c1.u[1] = __hip_atomic_load(hp + 3, __ATOMIC_RELAXED, __HIP_MEMORY_SCOPE_AGENT);
        c2.u[0] = __hip_atomic_load(hp + 4, __ATOMIC_RELAXED, __HIP_MEMORY_SCOPE_AGENT);
        c2.u[1] = __hip_atomic_load(hp + 5, __ATOMIC_RELAXED, __HIP_MEMORY_SCOPE_AGENT);
        c3.u[0] = __hip_atomic_load(hp + 6, __ATOMIC_RELAXED, __HIP_MEMORY_SCOPE_AGENT);
        c3.u[1] = __hip_atomic_load(hp + 7, __ATOMIC_RELAXED, __HIP_MEMORY_SCOPE_AGENT);
        q0 = c0.v; q1 = c1.v; q2 = c2.v; q3 = c3.v;
      }
      int ks = 4 + sseg;
      int base = (s_rt * 12 + ks) * 64 + s_lrow;
      ((half8*)At)[base +  0] = q0;
      ((half8*)At)[base + 16] = q1;
      ((half8*)At)[base + 32] = q2;
      ((half8*)At)[base + 48] = q3;
    }
    __syncthreads();

    // ---- MFMA: [32x384] @ [384x32], one 16x16 tile per wave, K-chain of 12
    f32x4 acc = {0.f, 0.f, 0.f, 0.f};
    #pragma unroll
    for (int ks = 0; ks < 12; ++ks)
      acc = __builtin_amdgcn_mfma_f32_16x16x32_f16(Af[ks * 64], Bf[ks * 64], acc, 0, 0, 0);
    pre_s[prow + 0][pcol] = acc[0];
    pre_s[prow + 1][pcol] = acc[1];
    pre_s[prow + 2][pcol] = acc[2];
    pre_s[prow + 3][pcol] = acc[3];
    __syncthreads();

    // ---- elementwise LSTM update; one (row, h-dim) per thread
    {
      float ip = pre_s[srow][sseg]      + bias_s[sseg];
      float fp = pre_s[srow][8 + sseg]  + bias_s[8 + sseg];
      float gp = pre_s[srow][16 + sseg] + bias_s[16 + sseg];
      float op = pre_s[srow][24 + sseg] + bias_s[24 + sseg];
      float iv = fast_sigmoid(ip);
      float fv = fast_sigmoid(fp);
      float gv = fast_tanh(gp);
      float ov = fast_sigmoid(op);
      float cv = fv * c_s[srow][sseg] + iv * gv;
      c_s[srow][sseg] = cv;
      float hv = ov * fast_tanh(cv);
      _Float16 hf = (_Float16)hv;
      unsigned short hb;
      __builtin_memcpy(&hb, &hf, 2);
      __hip_atomic_store(
          (unsigned short*)h_all + ((size_t)t * 256 + b0 + srow) * 256 + j * 8 + sseg,
          hb, __ATOMIC_RELAXED, __HIP_MEMORY_SCOPE_AGENT);
    }
    __syncthreads();   // drains vmcnt: all h stores complete before signalling

    // ---- inter-WG barrier (flag array, monotone counters; wave0 polls via ballot)
    if (wid == 0) {
      if (lane == 0)
        __hip_atomic_store(&flags[g * 32 + j], (unsigned)(t + 1),
                           __ATOMIC_RELEASE, __HIP_MEMORY_SCOPE_AGENT);
      int iters = 0;
      while (true) {
        unsigned v = (lane < 32)
            ? __hip_atomic_load(&flags[g * 32 + lane], __ATOMIC_RELAXED, __HIP_MEMORY_SCOPE_AGENT)
            : (unsigned)(t + 1);
        if (__ballot(v >= (unsigned)(t + 1)) == ~0ull) break;
        if (++iters > (1 << 17)) break;   // valve: garbage instead of hang
        __builtin_amdgcn_s_sleep(1);
      }
    }
    __syncthreads();
  }
}

// ---------------------------------------------------------------------------
// Head: per WG 64 rows of [T*B, H]; fused GEMM1->tanh->GEMM2->tanh->dot(W3).
// ---------------------------------------------------------------------------
__device__ __forceinline__ void head_gemm(const _Float16* __restrict__ A,
                                          const _Float16* __restrict__ Wf,
                                          const float* __restrict__ bvec,
                                          _Float16* __restrict__ Yd,
                                          int lane, int w)
{
  const half8* Af = (const half8*)A + w * 512 + lane;
  for (int ct = 0; ct < 16; ++ct) {
    const half8* Bf = (const half8*)Wf + ct * 512 + lane;
    f32x4 acc = {0.f, 0.f, 0.f, 0.f};
    #pragma unroll
    for (int ks = 0; ks < 8; ++ks)
      acc = __builtin_amdgcn_mfma_f32_16x16x32_f16(Af[ks * 64], Bf[ks * 64], acc, 0, 0, 0);
    int col = ct * 16 + (lane & 15);
    float bb = bvec[col];
    int ks2 = col >> 5, kg2 = (col >> 3) & 3, s2 = col & 7;
    #pragma unroll
    for (int r = 0; r < 4; ++r) {
      int row = w * 16 + ((lane >> 4) << 2) + r;
      float v = fast_tanh(acc[r] + bb);
      Yd[(((w * 8 + ks2) * 64) + kg2 * 16 + (row & 15)) * 8 + s2] = (_Float16)v;
    }
  }
}

__global__ void __launch_bounds__(256) head_kernel(
    const _Float16* __restrict__ h_all,
    const _Float16* __restrict__ W1f, const _Float16* __restrict__ W2f,
    const float* __restrict__ b1, const float* __restrict__ b2,
    const float* __restrict__ W3, const float* __restrict__ b3,
    float* __restrict__ out)
{
  __shared__ __align__(16) _Float16 A_s[16384];   // 32 KB (A rows, then y2)
  __shared__ __align__(16) _Float16 Y_s[16384];   // 32 KB (y1)
  const int tid = threadIdx.x;
  const size_t r0 = (size_t)blockIdx.x * 64;

  {
    int row = tid >> 2, seg = tid & 3;
    int rtl = row >> 4, lrow = row & 15;
    const half8* hp = (const half8*)(h_all + (r0 + row) * 256 + seg * 64);
    #pragma unroll
    for (int i = 0; i < 8; ++i) {
      int k0 = seg * 64 + i * 8;
      int ks = k0 >> 5, kg = (k0 >> 3) & 3;
      ((half8*)A_s)[(rtl * 8 + ks) * 64 + kg * 16 + lrow] = hp[i];
    }
  }
  __syncthreads();

  const int lane = tid & 63, w = tid >> 6;
  head_gemm(A_s, W1f, b1, Y_s, lane, w);   // y1 = tanh(h @ W1 + b1)
  __syncthreads();
  head_gemm(Y_s, W2f, b2, A_s, lane, w);   // y2 = tanh(y1 @ W2 + b2)
  __syncthreads();

  {
    int row = tid >> 2, part = tid & 3;
    int rtl = row >> 4, lrow = row & 15;
    float p = 0.f;
    #pragma unroll
    for (int kk = 0; kk < 8; ++kk) {
      int k0 = part * 64 + kk * 8;
      int ks = k0 >> 5, kg = (k0 >> 3) & 3;
      half8 y = ((const half8*)A_s)[(rtl * 8 + ks) * 64 + kg * 16 + lrow];
      #pragma unroll
      for (int i = 0; i < 8; ++i) p += (float)y[i] * W3[k0 + i];
    }
    p += __shfl_xor(p, 1);
    p += __shfl_xor(p, 2);
    if (part == 0) {
      size_t r = r0 + row;                 // r = t*256 + b
      int tt = (int)(r >> 8), bb = (int)(r & 255);
      out[(size_t)bb * 512 + tt] = p + b3[0];
    }
  }
}

// ---------------------------------------------------------------------------
extern "C" void kernel_launch(void* const* d_in, const int* in_sizes, int n_in,
                              void* d_out, int out_size, void* d_ws, size_t ws_size,
                              hipStream_t stream)
{
  const float* x  = (const float*)d_in[0];
  const float* Wx = (const float*)d_in[1];
  const float* Wh = (const float*)d_in[2];
  const float* b  = (const float*)d_in[3];
  const float* W1 = (const float*)d_in[4];
  const float* b1 = (const float*)d_in[5];
  const float* W2 = (const float*)d_in[6];
  const float* b2 = (const float*)d_in[7];
  const float* W3 = (const float*)d_in[8];
  const float* b3 = (const float*)d_in[9];
  float* out = (float*)d_out;

  char* ws = (char*)d_ws;
  unsigned* flags  = (unsigned*)ws;                       // 256 u32 (pad to 4 KB)
  _Float16* W1f    = (_Float16*)(ws + 4096);              // 128 KB
  _Float16* W2f    = (_Float16*)(ws + 4096 + 131072);     // 128 KB
  _Float16* h_all  = (_Float16*)(ws + 4096 + 262144);     // [512][256][256] f16 = 64 MB
  if (ws_size < (size_t)4096 + 262144 + 67108864) return; // insufficient scratch

  hipLaunchKernelGGL(prep_kernel, dim3(512), dim3(256), 0, stream,
                     W1, W2, W1f, W2f, flags);
  hipLaunchKernelGGL(lstm_rec_kernel, dim3(256), dim3(256), 0, stream,
                     x, Wx, Wh, b, h_all, flags);
  hipLaunchKernelGGL(head_kernel, dim3(2048), dim3(256), 0, stream,
                     h_all, W1f, W2f, b1, b2, W3, b3, out);
}